// Round 1
// baseline (1444.364 us; speedup 1.0000x reference)
//
#include <hip/hip_runtime.h>
#include <hip/hip_bf16.h>
#include <math.h>

#define N_NODES 100000
#define N_EDGES 3200000
#define IN_F 256
#define OUT_F 64
#define LRELU_ALPHA 0.2f

// ---------------------------------------------------------------------------
// init: zero out accumulator + denom, m = -inf
// ---------------------------------------------------------------------------
__global__ __launch_bounds__(256) void k_init(float* __restrict__ out,
                                              float* __restrict__ m,
                                              float* __restrict__ denom) {
  int i = blockIdx.x * 256 + threadIdx.x;
  if (i < N_NODES * OUT_F) out[i] = 0.f;
  if (i < N_NODES) {
    m[i] = __int_as_float(0xFF800000);  // -inf
    denom[i] = 0.f;
  }
}

// ---------------------------------------------------------------------------
// linear: h = x @ W^T + b ; s1 = h . a1 ; s2 = h . a2
// block = 256 threads = 4 waves; block handles 64 nodes.
// wave w computes outputs [16w, 16w+16) for all 64 nodes (lane = node).
// x staged through LDS in two 128-wide K halves; W via wave-uniform s_loads.
// ---------------------------------------------------------------------------
__global__ __launch_bounds__(256) void k_linear(
    const float* __restrict__ x, const float* __restrict__ W,
    const float* __restrict__ b, const float* __restrict__ a,
    float* __restrict__ h, float* __restrict__ s1, float* __restrict__ s2) {
  // stride 132 floats: 16B-aligned rows (528B), bank start = (4*nl + c) % 32
  __shared__ float xs[64 * 132];
  __shared__ float ps1[4][64];
  __shared__ float ps2[4][64];

  const int t = threadIdx.x;
  const int w = t >> 6;    // wave id = output block
  const int nl = t & 63;   // node within tile
  const int n0 = blockIdx.x * 64;
  const int ob = w * 16;   // output base for this wave

  float acc[16];
#pragma unroll
  for (int i = 0; i < 16; i++) acc[i] = b[ob + i];

#pragma unroll 1
  for (int half = 0; half < 2; half++) {
    // stage x[n0..n0+63][half*128 .. half*128+127] : 2048 float4s, 8 per thread
#pragma unroll
    for (int p = 0; p < 8; p++) {
      int f = p * 256 + t;  // 0..2047
      int row = f >> 5;     // 0..63
      int j4 = f & 31;      // 0..31
      int gn = n0 + row;
      float4 v = make_float4(0.f, 0.f, 0.f, 0.f);
      if (gn < N_NODES)
        v = *(const float4*)(x + (size_t)gn * IN_F + half * 128 + j4 * 4);
      *(float4*)(&xs[row * 132 + j4 * 4]) = v;
    }
    __syncthreads();

#pragma unroll 1
    for (int kh = 0; kh < 2; kh++) {  // K sub-tile of 64 within the half
      float xv[64];
#pragma unroll
      for (int j4 = 0; j4 < 16; j4++) {
        float4 v = *(const float4*)(&xs[nl * 132 + kh * 64 + j4 * 4]);
        xv[j4 * 4 + 0] = v.x;
        xv[j4 * 4 + 1] = v.y;
        xv[j4 * 4 + 2] = v.z;
        xv[j4 * 4 + 3] = v.w;
      }
      const int k0 = half * 128 + kh * 64;
#pragma unroll
      for (int i = 0; i < 16; i++) {
        const float* wr = W + (size_t)(ob + i) * IN_F + k0;  // wave-uniform
        float s = 0.f;
#pragma unroll
        for (int j = 0; j < 64; j++) s = fmaf(wr[j], xv[j], s);
        acc[i] += s;
      }
    }
    __syncthreads();  // before restage
  }

  // attention projections (partial per wave)
  float p1 = 0.f, p2 = 0.f;
#pragma unroll
  for (int i = 0; i < 16; i++) {
    p1 = fmaf(acc[i], a[ob + i], p1);
    p2 = fmaf(acc[i], a[OUT_F + ob + i], p2);
  }
  ps1[w][nl] = p1;
  ps2[w][nl] = p2;

  const int n = n0 + nl;
  if (n < N_NODES) {
#pragma unroll
    for (int i4 = 0; i4 < 4; i4++) {
      float4 v = make_float4(acc[i4 * 4 + 0], acc[i4 * 4 + 1],
                             acc[i4 * 4 + 2], acc[i4 * 4 + 3]);
      *(float4*)(h + (size_t)n * OUT_F + ob + i4 * 4) = v;
    }
  }
  __syncthreads();
  if (w == 0 && n < N_NODES) {
    s1[n] = ps1[0][nl] + ps1[1][nl] + ps1[2][nl] + ps1[3][nl];
    s2[n] = ps2[0][nl] + ps2[1][nl] + ps2[2][nl] + ps2[3][nl];
  }
}

// ---------------------------------------------------------------------------
// float atomic max via int/uint bit ordering
// ---------------------------------------------------------------------------
__device__ inline void atomicMaxF(float* addr, float val) {
  if (val >= 0.f) {
    atomicMax((int*)addr, __float_as_int(val));
  } else {
    atomicMin((unsigned int*)addr, (unsigned int)__float_as_int(val));
  }
}

// ---------------------------------------------------------------------------
// edge pass 1: e = leakyrelu(s1[src] + s2[dst]); m[dst] = max(...)
// ---------------------------------------------------------------------------
__global__ __launch_bounds__(256) void k_edge1(
    const int* __restrict__ src, const int* __restrict__ dst,
    const float* __restrict__ s1, const float* __restrict__ s2,
    float* __restrict__ ebuf, float* __restrict__ m) {
  int e = blockIdx.x * 256 + threadIdx.x;
  if (e >= N_EDGES) return;
  int s = src[e];
  int d = dst[e];
  float v = s1[s] + s2[d];
  v = v > 0.f ? v : LRELU_ALPHA * v;
  ebuf[e] = v;
  atomicMaxF(&m[d], v);
}

// ---------------------------------------------------------------------------
// edge pass 2: ex = exp(e - m[dst]); denom[dst] += ex
// ---------------------------------------------------------------------------
__global__ __launch_bounds__(256) void k_edge2(const int* __restrict__ dst,
                                               float* __restrict__ ebuf,
                                               const float* __restrict__ m,
                                               float* __restrict__ denom) {
  int e = blockIdx.x * 256 + threadIdx.x;
  if (e >= N_EDGES) return;
  int d = dst[e];
  float ex = expf(ebuf[e] - m[d]);
  ebuf[e] = ex;
  atomicAdd(&denom[d], ex);
}

// ---------------------------------------------------------------------------
// scatter: out[src, :] += (ex/denom[dst]) * h[dst, :]
// wave per edge (grid-stride), lane = feature
// ---------------------------------------------------------------------------
__global__ __launch_bounds__(256) void k_scatter(
    const int* __restrict__ src, const int* __restrict__ dst,
    const float* __restrict__ ebuf, const float* __restrict__ denom,
    const float* __restrict__ h, float* __restrict__ out) {
  int wid = (blockIdx.x * 256 + threadIdx.x) >> 6;
  int lane = threadIdx.x & 63;
  int nwaves = (gridDim.x * 256) >> 6;
  for (int e = wid; e < N_EDGES; e += nwaves) {
    int s = src[e];
    int d = dst[e];
    float att = ebuf[e] / denom[d];
    float hv = h[(size_t)d * OUT_F + lane];
    atomicAdd(&out[(size_t)s * OUT_F + lane], att * hv);
  }
}

// ---------------------------------------------------------------------------
// elu in place (alpha = 1): x>0 ? x : expm1(x)
// ---------------------------------------------------------------------------
__global__ __launch_bounds__(256) void k_elu(float* __restrict__ out) {
  int i = blockIdx.x * 256 + threadIdx.x;
  if (i >= N_NODES * OUT_F) return;
  float v = out[i];
  out[i] = v > 0.f ? v : expm1f(v);
}

// ---------------------------------------------------------------------------
extern "C" void kernel_launch(void* const* d_in, const int* in_sizes, int n_in,
                              void* d_out, int out_size, void* d_ws,
                              size_t ws_size, hipStream_t stream) {
  const int* adj = (const int*)d_in[0];
  const float* x = (const float*)d_in[1];
  const float* W = (const float*)d_in[2];
  const float* b = (const float*)d_in[3];
  const float* a = (const float*)d_in[4];
  float* out = (float*)d_out;

  float* ws = (float*)d_ws;
  float* h = ws;                    // 6,400,000
  float* ebuf = ws + 6400000;       // 3,200,000
  float* m = ws + 9600000;          // 100,000
  float* denom = ws + 9700000;      // 100,000
  float* s1v = ws + 9800000;        // 100,000
  float* s2v = ws + 9900000;        // 100,000

  const int* src = adj;
  const int* dst = adj + N_EDGES;

  k_init<<<25000, 256, 0, stream>>>(out, m, denom);
  k_linear<<<(N_NODES + 63) / 64, 256, 0, stream>>>(x, W, b, a, h, s1v, s2v);
  k_edge1<<<(N_EDGES + 255) / 256, 256, 0, stream>>>(src, dst, s1v, s2v, ebuf, m);
  k_edge2<<<(N_EDGES + 255) / 256, 256, 0, stream>>>(dst, ebuf, m, denom);
  k_scatter<<<6400, 256, 0, stream>>>(src, dst, ebuf, denom, h, out);
  k_elu<<<25000, 256, 0, stream>>>(out);
}

// Round 2
// 1365.957 us; speedup vs baseline: 1.0574x; 1.0574x over previous
//
#include <hip/hip_runtime.h>
#include <hip/hip_bf16.h>
#include <math.h>

#define N_NODES 100000
#define N_EDGES 3200000
#define IN_F 256
#define OUT_F 64
#define LRELU_ALPHA 0.2f

// ---------------------------------------------------------------------------
// init: cnt = 0, denom = 0, m = -inf  (out needs no init: aggregate overwrites)
// ---------------------------------------------------------------------------
__global__ __launch_bounds__(256) void k_init(int* __restrict__ cnt,
                                              float* __restrict__ m,
                                              float* __restrict__ denom) {
  int i = blockIdx.x * 256 + threadIdx.x;
  if (i < N_NODES) {
    cnt[i] = 0;
    m[i] = __int_as_float(0xFF800000);  // -inf
    denom[i] = 0.f;
  }
}

// ---------------------------------------------------------------------------
// linear: h = x @ W^T + b ; s1 = h . a1 ; s2 = h . a2
// block = 256 threads = 4 waves; block handles 64 nodes.
// wave w computes outputs [16w, 16w+16) for all 64 nodes (lane = node).
// ---------------------------------------------------------------------------
__global__ __launch_bounds__(256) void k_linear(
    const float* __restrict__ x, const float* __restrict__ W,
    const float* __restrict__ b, const float* __restrict__ a,
    float* __restrict__ h, float* __restrict__ s1, float* __restrict__ s2) {
  __shared__ float xs[64 * 132];
  __shared__ float ps1[4][64];
  __shared__ float ps2[4][64];

  const int t = threadIdx.x;
  const int w = t >> 6;
  const int nl = t & 63;
  const int n0 = blockIdx.x * 64;
  const int ob = w * 16;

  float acc[16];
#pragma unroll
  for (int i = 0; i < 16; i++) acc[i] = b[ob + i];

#pragma unroll 1
  for (int half = 0; half < 2; half++) {
#pragma unroll
    for (int p = 0; p < 8; p++) {
      int f = p * 256 + t;
      int row = f >> 5;
      int j4 = f & 31;
      int gn = n0 + row;
      float4 v = make_float4(0.f, 0.f, 0.f, 0.f);
      if (gn < N_NODES)
        v = *(const float4*)(x + (size_t)gn * IN_F + half * 128 + j4 * 4);
      *(float4*)(&xs[row * 132 + j4 * 4]) = v;
    }
    __syncthreads();

#pragma unroll 1
    for (int kh = 0; kh < 2; kh++) {
      float xv[64];
#pragma unroll
      for (int j4 = 0; j4 < 16; j4++) {
        float4 v = *(const float4*)(&xs[nl * 132 + kh * 64 + j4 * 4]);
        xv[j4 * 4 + 0] = v.x;
        xv[j4 * 4 + 1] = v.y;
        xv[j4 * 4 + 2] = v.z;
        xv[j4 * 4 + 3] = v.w;
      }
      const int k0 = half * 128 + kh * 64;
#pragma unroll
      for (int i = 0; i < 16; i++) {
        const float* wr = W + (size_t)(ob + i) * IN_F + k0;
        float s = 0.f;
#pragma unroll
        for (int j = 0; j < 64; j++) s = fmaf(wr[j], xv[j], s);
        acc[i] += s;
      }
    }
    __syncthreads();
  }

  float p1 = 0.f, p2 = 0.f;
#pragma unroll
  for (int i = 0; i < 16; i++) {
    p1 = fmaf(acc[i], a[ob + i], p1);
    p2 = fmaf(acc[i], a[OUT_F + ob + i], p2);
  }
  ps1[w][nl] = p1;
  ps2[w][nl] = p2;

  const int n = n0 + nl;
  if (n < N_NODES) {
#pragma unroll
    for (int i4 = 0; i4 < 4; i4++) {
      float4 v = make_float4(acc[i4 * 4 + 0], acc[i4 * 4 + 1],
                             acc[i4 * 4 + 2], acc[i4 * 4 + 3]);
      *(float4*)(h + (size_t)n * OUT_F + ob + i4 * 4) = v;
    }
  }
  __syncthreads();
  if (w == 0 && n < N_NODES) {
    s1[n] = ps1[0][nl] + ps1[1][nl] + ps1[2][nl] + ps1[3][nl];
    s2[n] = ps2[0][nl] + ps2[1][nl] + ps2[2][nl] + ps2[3][nl];
  }
}

__device__ inline void atomicMaxF(float* addr, float val) {
  if (val >= 0.f) {
    atomicMax((int*)addr, __float_as_int(val));
  } else {
    atomicMin((unsigned int*)addr, (unsigned int)__float_as_int(val));
  }
}

// ---------------------------------------------------------------------------
// edge pass 1: e = leakyrelu(s1[src]+s2[dst]); m[dst] max; degree hist on src
// ---------------------------------------------------------------------------
__global__ __launch_bounds__(256) void k_edge1(
    const int* __restrict__ src, const int* __restrict__ dst,
    const float* __restrict__ s1, const float* __restrict__ s2,
    float* __restrict__ ebuf, float* __restrict__ m, int* __restrict__ cnt) {
  int e = blockIdx.x * 256 + threadIdx.x;
  if (e >= N_EDGES) return;
  int s = src[e];
  int d = dst[e];
  float v = s1[s] + s2[d];
  v = v > 0.f ? v : LRELU_ALPHA * v;
  ebuf[e] = v;
  atomicMaxF(&m[d], v);
  atomicAdd(&cnt[s], 1);
}

// ---------------------------------------------------------------------------
// edge pass 2: ex = exp(e - m[dst]); denom[dst] += ex
// ---------------------------------------------------------------------------
__global__ __launch_bounds__(256) void k_edge2(const int* __restrict__ dst,
                                               float* __restrict__ ebuf,
                                               const float* __restrict__ m,
                                               float* __restrict__ denom) {
  int e = blockIdx.x * 256 + threadIdx.x;
  if (e >= N_EDGES) return;
  int d = dst[e];
  float ex = expf(ebuf[e] - m[d]);
  ebuf[e] = ex;
  atomicAdd(&denom[d], ex);
}

// ---------------------------------------------------------------------------
// single-block exclusive scan of cnt[0..N) -> row_ptr (and off working copy)
// 1024 threads = 16 waves; shuffle scan within wave, serial scan of wave sums
// ---------------------------------------------------------------------------
__global__ __launch_bounds__(1024) void k_scan(const int* __restrict__ cnt,
                                               int* __restrict__ row_ptr,
                                               int* __restrict__ off) {
  __shared__ int wavesum[16];
  __shared__ int waveoff[16];
  __shared__ int carry_s;
  const int t = threadIdx.x;
  const int wid = t >> 6;
  const int lane = t & 63;
  if (t == 0) carry_s = 0;
  __syncthreads();

  for (int base = 0; base < N_NODES; base += 1024) {
    int i = base + t;
    int v = (i < N_NODES) ? cnt[i] : 0;
    int val = v;
#pragma unroll
    for (int ofs = 1; ofs < 64; ofs <<= 1) {
      int u = __shfl_up(val, ofs, 64);
      if (lane >= ofs) val += u;
    }
    if (lane == 63) wavesum[wid] = val;
    __syncthreads();
    if (t == 0) {
      int run = carry_s;
#pragma unroll
      for (int w2 = 0; w2 < 16; w2++) {
        int s = wavesum[w2];
        waveoff[w2] = run;
        run += s;
      }
      carry_s = run;
    }
    __syncthreads();
    int excl = waveoff[wid] + (val - v);
    if (i < N_NODES) {
      row_ptr[i] = excl;
      off[i] = excl;
    }
    __syncthreads();
  }
  if (t == 0) row_ptr[N_NODES] = N_EDGES;
}

// ---------------------------------------------------------------------------
// place: att = ex/denom[dst]; src-sorted position via off[src]++
// ---------------------------------------------------------------------------
__global__ __launch_bounds__(256) void k_place(
    const int* __restrict__ src, const int* __restrict__ dst,
    const float* __restrict__ ebuf, const float* __restrict__ denom,
    int* __restrict__ off, float* __restrict__ att_s, int* __restrict__ dst_s) {
  int e = blockIdx.x * 256 + threadIdx.x;
  if (e >= N_EDGES) return;
  int s = src[e];
  int d = dst[e];
  float att = ebuf[e] / denom[d];
  int pos = atomicAdd(&off[s], 1);
  att_s[pos] = att;
  dst_s[pos] = d;
}

// ---------------------------------------------------------------------------
// aggregate: wave per node, lane = feature; acc += att * h[dst,:]; fused elu
// ---------------------------------------------------------------------------
__global__ __launch_bounds__(256) void k_aggregate(
    const int* __restrict__ row_ptr, const int* __restrict__ dst_s,
    const float* __restrict__ att_s, const float* __restrict__ h,
    float* __restrict__ out) {
  int node = (blockIdx.x * 256 + threadIdx.x) >> 6;
  int lane = threadIdx.x & 63;
  if (node >= N_NODES) return;
  int beg = row_ptr[node];
  int end = row_ptr[node + 1];
  float acc = 0.f;
  int i = beg;
  // 2-wide unroll for memory-level parallelism
  for (; i + 1 < end; i += 2) {
    int d0 = dst_s[i];
    int d1 = dst_s[i + 1];
    float a0 = att_s[i];
    float a1 = att_s[i + 1];
    float h0 = h[(size_t)d0 * OUT_F + lane];
    float h1 = h[(size_t)d1 * OUT_F + lane];
    acc = fmaf(a0, h0, acc);
    acc = fmaf(a1, h1, acc);
  }
  if (i < end) {
    int d0 = dst_s[i];
    float a0 = att_s[i];
    acc = fmaf(a0, h[(size_t)d0 * OUT_F + lane], acc);
  }
  acc = acc > 0.f ? acc : expm1f(acc);
  out[(size_t)node * OUT_F + lane] = acc;
}

// ---------------------------------------------------------------------------
extern "C" void kernel_launch(void* const* d_in, const int* in_sizes, int n_in,
                              void* d_out, int out_size, void* d_ws,
                              size_t ws_size, hipStream_t stream) {
  const int* adj = (const int*)d_in[0];
  const float* x = (const float*)d_in[1];
  const float* W = (const float*)d_in[2];
  const float* b = (const float*)d_in[3];
  const float* a = (const float*)d_in[4];
  float* out = (float*)d_out;

  float* ws = (float*)d_ws;
  float* h = ws;                          // 6,400,000 f
  float* ebuf = ws + 6400000;             // 3,200,000 f
  float* m = ws + 9600000;                // 100,000 f
  float* denom = ws + 9700000;            // 100,000 f
  float* s1v = ws + 9800000;              // 100,000 f
  float* s2v = ws + 9900000;              // 100,000 f
  int* cnt = (int*)(ws + 10000000);       // 100,000 i (doubles as off)
  int* row_ptr = (int*)(ws + 10100000);   // 100,001 i
  int* dst_s = (int*)(ws + 10200004);     // 3,200,000 i
  float* att_s = ws + 13400004;           // 3,200,000 f
  // total ~16.6M floats = 66.4 MB

  const int* src = adj;
  const int* dst = adj + N_EDGES;

  k_init<<<(N_NODES + 255) / 256, 256, 0, stream>>>(cnt, m, denom);
  k_linear<<<(N_NODES + 63) / 64, 256, 0, stream>>>(x, W, b, a, h, s1v, s2v);
  k_edge1<<<(N_EDGES + 255) / 256, 256, 0, stream>>>(src, dst, s1v, s2v, ebuf,
                                                     m, cnt);
  k_edge2<<<(N_EDGES + 255) / 256, 256, 0, stream>>>(dst, ebuf, m, denom);
  k_scan<<<1, 1024, 0, stream>>>(cnt, row_ptr, cnt /* off reuse */);
  k_place<<<(N_EDGES + 255) / 256, 256, 0, stream>>>(src, dst, ebuf, denom,
                                                     cnt, att_s, dst_s);
  k_aggregate<<<(N_NODES * 64 + 255) / 256, 256, 0, stream>>>(row_ptr, dst_s,
                                                              att_s, h, out);
}

// Round 3
// 913.755 us; speedup vs baseline: 1.5807x; 1.4949x over previous
//
#include <hip/hip_runtime.h>
#include <math.h>

#define N_NODES 100000
#define N_EDGES 3200000
#define IN_F 256
#define OUT_F 64
#define LRELU_ALPHA 0.2f
#define NB_SCAN 98  // ceil(100000/1024)

typedef unsigned short u16;
typedef __attribute__((ext_vector_type(8))) short short8;
typedef __attribute__((ext_vector_type(4))) float floatx4;

__device__ inline u16 f2bf(float f) {  // RNE fp32 -> bf16
  unsigned u = __float_as_uint(f);
  u += 0x7FFFu + ((u >> 16) & 1u);
  return (u16)(u >> 16);
}
__device__ inline float bf2f(u16 h) {
  return __uint_as_float(((unsigned)h) << 16);
}

// ---------------------------------------------------------------------------
// init: cnt = 0, denom = 0, m = -inf
// ---------------------------------------------------------------------------
__global__ __launch_bounds__(256) void k_init(int* __restrict__ cnt,
                                              float* __restrict__ m,
                                              float* __restrict__ denom) {
  int i = blockIdx.x * 256 + threadIdx.x;
  if (i < N_NODES) {
    cnt[i] = 0;
    m[i] = __int_as_float(0xFF800000);
    denom[i] = 0.f;
  }
}

// ---------------------------------------------------------------------------
// W fp32 -> bf16 (once per call; 16384 elements)
// ---------------------------------------------------------------------------
__global__ __launch_bounds__(256) void k_wconv(const float* __restrict__ W,
                                               u16* __restrict__ Wbf) {
  int i = blockIdx.x * 256 + threadIdx.x;
  if (i < OUT_F * IN_F) Wbf[i] = f2bf(W[i]);
}

// ---------------------------------------------------------------------------
// linear via bf16 MFMA: h = x@W^T + b (stored bf16); s1 = h.a1; s2 = h.a2
// block = 256 thr = 4 waves; wave w: nodes [blk*64+w*16, +16), all 64 outputs.
// A-frag: x fp32 loaded direct from global, converted in-reg.
// B-frag: W bf16 staged in LDS, row stride 264 (pad 8) to break bank conflicts.
// mfma_f32_16x16x32_bf16: A[m=lane&15][k=q*8+j], B[k=q*8+j][n=lane&15],
// D col=lane&15, row=q*4+reg.
// ---------------------------------------------------------------------------
__global__ __launch_bounds__(256) void k_linear(
    const float* __restrict__ x, const u16* __restrict__ Wbf,
    const float* __restrict__ b, const float* __restrict__ a,
    u16* __restrict__ hbf, float* __restrict__ s1, float* __restrict__ s2) {
  __shared__ u16 Wlds[64 * 264];  // 33792 B

  const int t = threadIdx.x;
  // stage W: 2048 16B chunks, 8 per thread
#pragma unroll
  for (int p = 0; p < 8; p++) {
    int c = p * 256 + t;
    int row = c >> 5;          // 32 chunks of 8 bf16 per 256-wide row
    int kc = (c & 31) * 8;
    *(short8*)&Wlds[row * 264 + kc] = *(const short8*)&Wbf[row * 256 + kc];
  }
  __syncthreads();

  const int w = t >> 6;
  const int lane = t & 63;
  const int col = lane & 15;
  const int q = lane >> 4;
  const int m0 = blockIdx.x * 64 + w * 16;

  floatx4 acc[4];
#pragma unroll
  for (int nt = 0; nt < 4; nt++) acc[nt] = (floatx4){0.f, 0.f, 0.f, 0.f};

  int mrow = m0 + col;
  if (mrow > N_NODES - 1) mrow = N_NODES - 1;  // clamp; result discarded
  const float* xrow = x + (size_t)mrow * IN_F + q * 8;

#pragma unroll
  for (int kk = 0; kk < 8; kk++) {
    float4 f0 = *(const float4*)(xrow + kk * 32);
    float4 f1 = *(const float4*)(xrow + kk * 32 + 4);
    short8 af;
    af[0] = (short)f2bf(f0.x);
    af[1] = (short)f2bf(f0.y);
    af[2] = (short)f2bf(f0.z);
    af[3] = (short)f2bf(f0.w);
    af[4] = (short)f2bf(f1.x);
    af[5] = (short)f2bf(f1.y);
    af[6] = (short)f2bf(f1.z);
    af[7] = (short)f2bf(f1.w);
#pragma unroll
    for (int nt = 0; nt < 4; nt++) {
      short8 bfr = *(const short8*)&Wlds[(nt * 16 + col) * 264 + kk * 32 + q * 8];
      acc[nt] = __builtin_amdgcn_mfma_f32_16x16x32_bf16(af, bfr, acc[nt], 0, 0, 0);
    }
  }

  // epilogue: bias, h store (bf16), s1/s2 shuffle-reduce over 16 cols
  float bv[4], a1v[4], a2v[4];
#pragma unroll
  for (int nt = 0; nt < 4; nt++) {
    bv[nt] = b[nt * 16 + col];
    a1v[nt] = a[nt * 16 + col];
    a2v[nt] = a[OUT_F + nt * 16 + col];
  }
#pragma unroll
  for (int r = 0; r < 4; r++) {
    int node = m0 + q * 4 + r;
    float p1 = 0.f, p2 = 0.f;
#pragma unroll
    for (int nt = 0; nt < 4; nt++) {
      float hv = acc[nt][r] + bv[nt];
      if (node < N_NODES) hbf[(size_t)node * OUT_F + nt * 16 + col] = f2bf(hv);
      p1 = fmaf(hv, a1v[nt], p1);
      p2 = fmaf(hv, a2v[nt], p2);
    }
#pragma unroll
    for (int s = 1; s < 16; s <<= 1) {
      p1 += __shfl_xor(p1, s, 16);
      p2 += __shfl_xor(p2, s, 16);
    }
    if (col == 0 && node < N_NODES) {
      s1[node] = p1;
      s2[node] = p2;
    }
  }
}

__device__ inline void atomicMaxF(float* addr, float val) {
  if (val >= 0.f) {
    atomicMax((int*)addr, __float_as_int(val));
  } else {
    atomicMin((unsigned int*)addr, (unsigned int)__float_as_int(val));
  }
}

// ---------------------------------------------------------------------------
// edge pass 1: e = leakyrelu(s1[src]+s2[dst]); m[dst] max; degree hist on src
// ---------------------------------------------------------------------------
__global__ __launch_bounds__(256) void k_edge1(
    const int* __restrict__ src, const int* __restrict__ dst,
    const float* __restrict__ s1, const float* __restrict__ s2,
    float* __restrict__ ebuf, float* __restrict__ m, int* __restrict__ cnt) {
  int e = blockIdx.x * 256 + threadIdx.x;
  if (e >= N_EDGES) return;
  int s = src[e];
  int d = dst[e];
  float v = s1[s] + s2[d];
  v = v > 0.f ? v : LRELU_ALPHA * v;
  ebuf[e] = v;
  atomicMaxF(&m[d], v);
  atomicAdd(&cnt[s], 1);
}

// ---------------------------------------------------------------------------
// edge pass 2: ex = exp(e - m[dst]); denom[dst] += ex
// ---------------------------------------------------------------------------
__global__ __launch_bounds__(256) void k_edge2(const int* __restrict__ dst,
                                               float* __restrict__ ebuf,
                                               const float* __restrict__ m,
                                               float* __restrict__ denom) {
  int e = blockIdx.x * 256 + threadIdx.x;
  if (e >= N_EDGES) return;
  int d = dst[e];
  float ex = expf(ebuf[e] - m[d]);
  ebuf[e] = ex;
  atomicAdd(&denom[d], ex);
}

// ---------------------------------------------------------------------------
// hierarchical scan: (1) per-block sums (2) scan of 98 sums (3) full scan
// ---------------------------------------------------------------------------
__global__ __launch_bounds__(256) void k_scan1(const int* __restrict__ cnt,
                                               int* __restrict__ bsum) {
  __shared__ int wsum[4];
  int t = threadIdx.x;
  int base = blockIdx.x * 1024 + t * 4;
  int s = 0;
#pragma unroll
  for (int j = 0; j < 4; j++) {
    int i = base + j;
    s += (i < N_NODES) ? cnt[i] : 0;
  }
#pragma unroll
  for (int ofs = 32; ofs >= 1; ofs >>= 1) s += __shfl_xor(s, ofs, 64);
  if ((t & 63) == 0) wsum[t >> 6] = s;
  __syncthreads();
  if (t == 0) bsum[blockIdx.x] = wsum[0] + wsum[1] + wsum[2] + wsum[3];
}

__global__ __launch_bounds__(64) void k_scan2(const int* __restrict__ bsum,
                                              int* __restrict__ bexcl) {
  int lane = threadIdx.x;
  int carry = 0;
  for (int base = 0; base < NB_SCAN; base += 64) {
    int i = base + lane;
    int v = (i < NB_SCAN) ? bsum[i] : 0;
    int val = v;
#pragma unroll
    for (int ofs = 1; ofs < 64; ofs <<= 1) {
      int u = __shfl_up(val, ofs, 64);
      if (lane >= ofs) val += u;
    }
    if (i < NB_SCAN) bexcl[i] = carry + val - v;
    carry += __shfl(val, 63, 64);
  }
}

__global__ __launch_bounds__(256) void k_scan3(const int* __restrict__ cnt,
                                               const int* __restrict__ bexcl,
                                               int* __restrict__ row_ptr,
                                               int* __restrict__ off) {
  __shared__ int wsum[4];
  __shared__ int woff[4];
  int t = threadIdx.x;
  int lane = t & 63;
  int wid = t >> 6;
  int base = blockIdx.x * 1024 + t * 4;
  int v[4];
  int tsum = 0;
#pragma unroll
  for (int j = 0; j < 4; j++) {
    int i = base + j;
    v[j] = (i < N_NODES) ? cnt[i] : 0;
    tsum += v[j];
  }
  int val = tsum;
#pragma unroll
  for (int ofs = 1; ofs < 64; ofs <<= 1) {
    int u = __shfl_up(val, ofs, 64);
    if (lane >= ofs) val += u;
  }
  if (lane == 63) wsum[wid] = val;
  __syncthreads();
  if (t == 0) {
    int run = 0;
#pragma unroll
    for (int w2 = 0; w2 < 4; w2++) {
      woff[w2] = run;
      run += wsum[w2];
    }
  }
  __syncthreads();
  int excl = bexcl[blockIdx.x] + woff[wid] + (val - tsum);
#pragma unroll
  for (int j = 0; j < 4; j++) {
    int i = base + j;
    if (i < N_NODES) {
      row_ptr[i] = excl;
      off[i] = excl;
    }
    excl += v[j];
  }
  if (blockIdx.x == 0 && t == 0) row_ptr[N_NODES] = N_EDGES;
}

// ---------------------------------------------------------------------------
// place: att = ex/denom[dst]; (att, dst) packed 8B into src-sorted position
// ---------------------------------------------------------------------------
__global__ __launch_bounds__(256) void k_place(
    const int* __restrict__ src, const int* __restrict__ dst,
    const float* __restrict__ ebuf, const float* __restrict__ denom,
    int* __restrict__ off, float2* __restrict__ pair) {
  int e = blockIdx.x * 256 + threadIdx.x;
  if (e >= N_EDGES) return;
  int s = src[e];
  int d = dst[e];
  float att = ebuf[e] / denom[d];
  int pos = atomicAdd(&off[s], 1);
  pair[pos] = make_float2(att, __int_as_float(d));
}

// ---------------------------------------------------------------------------
// aggregate: wave per node, lane = feature; acc += att * h_bf16[dst,:]; elu
// ---------------------------------------------------------------------------
__global__ __launch_bounds__(256) void k_aggregate(
    const int* __restrict__ row_ptr, const float2* __restrict__ pair,
    const u16* __restrict__ hbf, float* __restrict__ out) {
  int node = (blockIdx.x * 256 + threadIdx.x) >> 6;
  int lane = threadIdx.x & 63;
  if (node >= N_NODES) return;
  int beg = row_ptr[node];
  int end = row_ptr[node + 1];
  float acc = 0.f;
  int i = beg;
  for (; i + 3 < end; i += 4) {
    float2 p0 = pair[i];
    float2 p1 = pair[i + 1];
    float2 p2 = pair[i + 2];
    float2 p3 = pair[i + 3];
    float h0 = bf2f(hbf[(size_t)__float_as_int(p0.y) * OUT_F + lane]);
    float h1 = bf2f(hbf[(size_t)__float_as_int(p1.y) * OUT_F + lane]);
    float h2 = bf2f(hbf[(size_t)__float_as_int(p2.y) * OUT_F + lane]);
    float h3 = bf2f(hbf[(size_t)__float_as_int(p3.y) * OUT_F + lane]);
    acc = fmaf(p0.x, h0, acc);
    acc = fmaf(p1.x, h1, acc);
    acc = fmaf(p2.x, h2, acc);
    acc = fmaf(p3.x, h3, acc);
  }
  for (; i < end; i++) {
    float2 p = pair[i];
    acc = fmaf(p.x, bf2f(hbf[(size_t)__float_as_int(p.y) * OUT_F + lane]), acc);
  }
  acc = acc > 0.f ? acc : expm1f(acc);
  out[(size_t)node * OUT_F + lane] = acc;
}

// ---------------------------------------------------------------------------
extern "C" void kernel_launch(void* const* d_in, const int* in_sizes, int n_in,
                              void* d_out, int out_size, void* d_ws,
                              size_t ws_size, hipStream_t stream) {
  const int* adj = (const int*)d_in[0];
  const float* x = (const float*)d_in[1];
  const float* W = (const float*)d_in[2];
  const float* b = (const float*)d_in[3];
  const float* a = (const float*)d_in[4];
  float* out = (float*)d_out;

  float* ws = (float*)d_ws;
  float* ebuf = ws;                            // 3,200,000 f
  float* m = ws + 3200000;                     // 100,000 f
  float* denom = ws + 3300000;                 // 100,000 f
  float* s1v = ws + 3400000;                   // 100,000 f
  float* s2v = ws + 3500000;                   // 100,000 f
  int* cnt = (int*)(ws + 3600000);             // 100,000 i (reused as off)
  int* row_ptr = (int*)(ws + 3700000);         // 100,001 i (pad to 100,032)
  int* bsum = (int*)(ws + 3800032);            // 128 i
  int* bexcl = (int*)(ws + 3800160);           // 128 i
  float2* pair = (float2*)(ws + 3800288);      // 3,200,000 float2 (8B aligned)
  u16* hbf = (u16*)(ws + 10200288);            // 6,400,000 u16
  u16* Wbf = (u16*)(ws + 13400288);            // 16,384 u16
  // total ~13.41M floats = 53.6 MB

  const int* src = adj;
  const int* dst = adj + N_EDGES;

  k_init<<<(N_NODES + 255) / 256, 256, 0, stream>>>(cnt, m, denom);
  k_wconv<<<64, 256, 0, stream>>>(W, Wbf);
  k_linear<<<(N_NODES + 63) / 64, 256, 0, stream>>>(x, Wbf, b, a, hbf, s1v, s2v);
  k_edge1<<<(N_EDGES + 255) / 256, 256, 0, stream>>>(src, dst, s1v, s2v, ebuf,
                                                     m, cnt);
  k_edge2<<<(N_EDGES + 255) / 256, 256, 0, stream>>>(dst, ebuf, m, denom);
  k_scan1<<<NB_SCAN, 256, 0, stream>>>(cnt, bsum);
  k_scan2<<<1, 64, 0, stream>>>(bsum, bexcl);
  k_scan3<<<NB_SCAN, 256, 0, stream>>>(cnt, bexcl, row_ptr, cnt /* off */);
  k_place<<<(N_EDGES + 255) / 256, 256, 0, stream>>>(src, dst, ebuf, denom,
                                                     cnt, pair);
  k_aggregate<<<(N_NODES * 64 + 255) / 256, 256, 0, stream>>>(row_ptr, pair,
                                                              hbf, out);
}